// Round 6
// baseline (108.217 us; speedup 1.0000x reference)
//
#include <hip/hip_runtime.h>
#include <math.h>

// Quantum circuit simulator: BATCH=2048 states x 1024 complex amplitudes,
// QDEPTH=8 layers of StronglyEntanglingLayers (10 Rot gates + 10 CNOTs).
//
// Round-20: fused single-dispatch (r19 WIN on total: removed ~19us of
// launch/dependency overhead; total = kernel + 32.9us fixed) + coeff
// distribution via v_readlane instead of LDS (r19's kernel regression
// 51.6->69.4us = 640 coeff ds_read/wave on the shared lgkmcnt queue).
//  - lane g computes gate g coeffs (cA; lanes 0..15 also gates 64..79
//    in cB). Each gate: 8 v_readlane -> SGPR scalars. No memory, no
//    lgkmcnt, ~1 issue slot each.
//  - CNOT gt-table via GF(2) linearity: gt[t] = XOR_{b in t} G_b with
//    G_b = word(g_l(1<<b)) -> 32 values packed in ONE VGPR (gv), 4
//    readlane + ~4 s_xor per layer replace the 16-entry table.
//  - ga (per-lane divergent) stays in LDS gaT[8][64]; 1 conflict-free
//    ds_read/layer, double-buffered one layer ahead (consumed next layer
//    -> latency fully hidden).
//  - layers 0..5: runtime loop (readlane idx = l*10+q via SALU, cA only);
//    layers 6,7 unrolled (compile-time cA/cB register select).
// Gate/CNOT core byte-identical to r15 (validated):
//  - state packed over t: zr[k]=(re[t=k],re[t=k+8]), zi likewise ->
//    element-wise v_pk_fma_f32 with scalar coeffs (r13 WIN).
//  - wires 9..7: cross-pack register gates; wire 6: in-pack half-swap.
//  - wires 5..2: DPP row ops; wires 1,0: permlane{16,32}_swap (VALU).
//  - CNOT: composed GF(2)-linear permutation, one LDS round trip, t-major
//    b32 SoA word(i)=(i&15)*64+(i>>4) (only layout measured conflict-free).
//    Merged re/im planes -> ds_*2st64_b32 pairing.
//  - No __syncthreads: single wave; per-wave DS ops are FIFO-ordered.
// Session ladder: r15 51.6 (best kernel) / r16 56.4 F / r17 54.2 F /
// r18 71 F / r19 69.4 kernel but 102.3 total (best total).

#define WIRES   10
#define NSTATE  1024
#define QDEPTH  8
#define NBATCH  2048
#define NGATES  (QDEPTH * WIRES)

typedef float v2f __attribute__((ext_vector_type(2)));
typedef unsigned int v2u __attribute__((ext_vector_type(2)));
static __device__ __forceinline__ v2f s2(float x) { return (v2f){x, x}; }

__device__ __forceinline__ int perm_g(int j, int r) {
#pragma unroll
    for (int q = WIRES - 1; q >= 0; --q) {
        const int cb = 9 - q;
        const int tb = 9 - ((q + r) % WIRES);
        j ^= ((j >> cb) & 1) << tb;
    }
    return j;
}

// uniform broadcast from a lane: VALU v_readlane -> SGPR, no memory
#if __has_builtin(__builtin_amdgcn_readlane)
static __device__ __forceinline__ int rli(int v, int idx) {
    return __builtin_amdgcn_readlane(v, idx);
}
#else
static __device__ __forceinline__ int rli(int v, int idx) {
    return __shfl(v, idx, 64);
}
#endif
static __device__ __forceinline__ float rlf(float v, int idx) {
    return __int_as_float(rli(__float_as_int(v), idx));
}

// DPP cross-lane move (VALU pipe, rows of 16 lanes) — validated r9/r10/r13
template<int CTRL>
__device__ __forceinline__ float dppmov(float x) {
    return __int_as_float(__builtin_amdgcn_update_dpp(
        0, __float_as_int(x), CTRL, 0xF, 0xF, true));
}
#define FX1(v)  dppmov<0xB1>(v)
#define FX2(v)  dppmov<0x4E>(v)
#define FX4(v)  dppmov<0x1B>(dppmov<0x141>(v))
#define FX8(v)  dppmov<0x128>(v)

#if __has_builtin(__builtin_amdgcn_permlane16_swap)
static __device__ __forceinline__ float pl16swap(float x) {
    const v2u r = __builtin_amdgcn_permlane16_swap(
        __float_as_uint(x), __float_as_uint(x), false, false);
    return __uint_as_float((threadIdx.x & 16) ? r.x : r.y);
}
#define FX16(v) pl16swap(v)
#else
#define FX16(v) __shfl_xor((v), 16, 64)
#endif

#if __has_builtin(__builtin_amdgcn_permlane32_swap)
static __device__ __forceinline__ float pl32swap(float x) {
    const v2u r = __builtin_amdgcn_permlane32_swap(
        __float_as_uint(x), __float_as_uint(x), false, false);
    return __uint_as_float((threadIdx.x & 32) ? r.x : r.y);
}
#define FX32(v) pl32swap(v)
#else
#define FX32(v) __shfl_xor((v), 32, 64)
#endif

// Rot(phi,theta,omega) 2x2 unitary coeffs for gate g (from weights)
__device__ __forceinline__ void gate_coeffs(
    const float* __restrict__ w, int g, float (&c8)[8])
{
    const float phi   = tanhf(w[g * 3 + 0]);
    const float theta = tanhf(w[g * 3 + 1]);
    const float omega = tanhf(w[g * 3 + 2]);
    const float c  = cosf(theta * 0.5f);
    const float sn = sinf(theta * 0.5f);
    const float a  = 0.5f * (phi + omega);
    const float bb = 0.5f * (phi - omega);
    const float ca = cosf(a),  sa = sinf(a);
    const float cb = cosf(bb), sb = sinf(bb);
    // U00 = e^{-ia} c ; U01 = -e^{+ib} s ; U10 = e^{-ib} s ; U11 = e^{+ia} c
    c8[0] =  ca * c;  c8[1] = -sa * c;
    c8[2] = -cb * sn; c8[3] = -sb * sn;
    c8[4] =  cb * sn; c8[5] = -sb * sn;
    c8[6] =  ca * c;  c8[7] =  sa * c;
}

// ---- gate bodies; expect `getc(q,j)`, `lane`, `zr`, `zi` in scope ----
#define LOCAL_GATE(Q, MASK)                                                   \
    {                                                                         \
        const float u00r=getc(Q,0), u00i=getc(Q,1), u01r=getc(Q,2),           \
                    u01i=getc(Q,3), u10r=getc(Q,4), u10i=getc(Q,5),           \
                    u11r=getc(Q,6), u11i=getc(Q,7);                           \
        _Pragma("unroll")                                                     \
        for (int k0 = 0; k0 < 8; ++k0) {                                      \
            if (k0 & (MASK)) continue;                                        \
            const int k1 = k0 | (MASK);                                       \
            const v2f a0r = zr[k0], a0i = zi[k0];                             \
            const v2f a1r = zr[k1], a1i = zi[k1];                             \
            zr[k0] = s2(u00r)*a0r - s2(u00i)*a0i + s2(u01r)*a1r - s2(u01i)*a1i;\
            zi[k0] = s2(u00r)*a0i + s2(u00i)*a0r + s2(u01r)*a1i + s2(u01i)*a1r;\
            zr[k1] = s2(u10r)*a0r - s2(u10i)*a0i + s2(u11r)*a1r - s2(u11i)*a1i;\
            zi[k1] = s2(u10r)*a0i + s2(u10i)*a0r + s2(u11r)*a1i + s2(u11i)*a1r;\
        }                                                                     \
    }

#define HSWAP_GATE(Q)                                                         \
    {                                                                         \
        const float u00r=getc(Q,0), u00i=getc(Q,1), u01r=getc(Q,2),           \
                    u01i=getc(Q,3), u10r=getc(Q,4), u10i=getc(Q,5),           \
                    u11r=getc(Q,6), u11i=getc(Q,7);                           \
        const v2f pAr = (v2f){u00r, u11r};                                    \
        const v2f pAi = (v2f){u00i, u11i};                                    \
        const v2f pBr = (v2f){u01r, u10r};                                    \
        const v2f pBi = (v2f){u01i, u10i};                                    \
        _Pragma("unroll")                                                     \
        for (int k = 0; k < 8; ++k) {                                         \
            const v2f r  = zr[k], i = zi[k];                                  \
            const v2f rs = __builtin_shufflevector(r, r, 1, 0);               \
            const v2f is = __builtin_shufflevector(i, i, 1, 0);               \
            zr[k] = pAr*r - pAi*i + pBr*rs - pBi*is;                          \
            zi[k] = pAr*i + pAi*r + pBr*is + pBi*rs;                          \
        }                                                                     \
    }

#define LANE_GATE(Q, J, FETCH)                                                \
    {                                                                         \
        const float u00r=getc(Q,0), u00i=getc(Q,1), u01r=getc(Q,2),           \
                    u01i=getc(Q,3), u10r=getc(Q,4), u10i=getc(Q,5),           \
                    u11r=getc(Q,6), u11i=getc(Q,7);                           \
        const bool hi = (lane >> (J)) & 1;                                    \
        const float c0r = hi ? u11r : u00r, c0i = hi ? u11i : u00i;           \
        const float c1r = hi ? u10r : u01r, c1i = hi ? u10i : u01i;           \
        _Pragma("unroll")                                                     \
        for (int k = 0; k < 8; ++k) {                                         \
            v2f pr, pi;                                                       \
            pr.x = FETCH(zr[k].x); pr.y = FETCH(zr[k].y);                     \
            pi.x = FETCH(zi[k].x); pi.y = FETCH(zi[k].y);                     \
            const v2f sr = zr[k], si = zi[k];                                 \
            zr[k] = s2(c0r)*sr - s2(c0i)*si + s2(c1r)*pr - s2(c1i)*pi;        \
            zi[k] = s2(c0r)*si + s2(c0i)*sr + s2(c1r)*pi + s2(c1i)*pr;        \
        }                                                                     \
    }

// one full layer: 10 rotation gates + composed-CNOT LDS round trip.
// G0..G3 = gt-basis (SGPR); ga = word(g_l(lane<<4)) per-lane.
template<typename GetC>
__device__ __forceinline__ void layer_body(
    v2f (&zr)[8], v2f (&zi)[8], GetC getc,
    const int G0, const int G1, const int G2, const int G3,
    const int ga, float* __restrict__ lds, const int lane)
{
    LOCAL_GATE(9, 1)
    LOCAL_GATE(8, 2)
    LOCAL_GATE(7, 4)
    HSWAP_GATE(6)
    LANE_GATE(5, 0, FX1)
    LANE_GATE(4, 1, FX2)
    LANE_GATE(3, 2, FX4)
    LANE_GATE(2, 3, FX8)
    LANE_GATE(1, 4, FX16)
    LANE_GATE(0, 5, FX32)

    // CNOT write: word(i) = t*64 + lane; 4 stores/k share base ->
    // 2x ds_write2st64_b32. Conflict-free (bank = lane mod 32).
#pragma unroll
    for (int k = 0; k < 8; ++k) {
        const int w = k * 64 + lane;
        lds[w]        = zr[k].x;
        lds[w + 512]  = zr[k].y;
        lds[w + 1024] = zi[k].x;
        lds[w + 1536] = zi[k].y;
    }
    // gt[k] = XOR of basis (SALU); a0/a1 per k; single-wave DS FIFO ->
    // no barrier. (re,im) share base -> 2x ds_read2st64_b32.
    const int s01 = G0 ^ G1;
    const int gkt[8] = {0, G0, G1, s01, G2, G2 ^ G0, G2 ^ G1, G2 ^ s01};
#pragma unroll
    for (int k = 0; k < 8; ++k) {
        const int a0 = ga ^ gkt[k];
        const int a1 = a0 ^ G3;
        zr[k].x = lds[a0]; zi[k].x = lds[a0 + 1024];
        zr[k].y = lds[a1]; zi[k].y = lds[a1 + 1024];
    }
}

__global__ __launch_bounds__(64) void qsim_rl(
    const float* __restrict__ x,
    const float* __restrict__ weights,
    float* __restrict__ out,
    const int interleaved)
{
    __shared__ float lds[2 * NSTATE];       // CNOT buffer: re [0,1024), im +1024
    __shared__ int   gaT[QDEPTH * 64];      // word(g_l(lane<<4)) per lane

    const int lane = threadIdx.x;           // 0..63
    const int b    = blockIdx.x;

    // ---- prologue: coeffs in registers (lane g -> gate g), tables ----
    float cA[8], cB[8];
    gate_coeffs(weights, lane, cA);                 // gates 0..63
    gate_coeffs(weights, 64 + (lane & 15), cB);     // gates 64..79 (lanes 0..15)

    int gv;                                 // G-basis: lane = l*4+b (l<8,b<4)
    {
        const int lg = (lane >> 2) & 7;
        const int bb = lane & 3;
        const int j  = perm_g(1 << bb, lg + 1);
        gv = ((j & 15) << 6) | (j >> 4);
    }
#pragma unroll
    for (int l = 0; l < QDEPTH; ++l) {      // ranges r_l = l+1 (l<9)
        const int j = perm_g(lane << 4, l + 1);
        gaT[l * 64 + lane] = ((j & 15) << 6) | (j >> 4);
    }

    // ---- load 16 contiguous amplitudes (real input, imag = 0) ----
    v2f zr[8], zi[8];
    const float4* __restrict__ x4 =
        (const float4*)(x + ((size_t)b << 10) + (lane << 4));
    {
        const float4 v0 = x4[0], v1 = x4[1], v2 = x4[2], v3 = x4[3];
        zr[0].x=v0.x; zr[1].x=v0.y; zr[2].x=v0.z; zr[3].x=v0.w;
        zr[4].x=v1.x; zr[5].x=v1.y; zr[6].x=v1.z; zr[7].x=v1.w;
        zr[0].y=v2.x; zr[1].y=v2.y; zr[2].y=v2.z; zr[3].y=v2.w;
        zr[4].y=v3.x; zr[5].y=v3.y; zr[6].y=v3.z; zr[7].y=v3.w;
#pragma unroll
        for (int k = 0; k < 8; ++k) zi[k] = (v2f){0.f, 0.f};
    }

    // ga double-buffered one layer ahead (latency hidden under gates)
    int ga = gaT[lane];                     // layer 0 (DS FIFO after init writes)

    // ---- layers 0..5: all gates in cA; runtime readlane index ----
#pragma unroll 1
    for (int l = 0; l < 6; ++l) {
        const int sb = l * 10;
        const int G0 = rli(gv, 4 * l + 0);
        const int G1 = rli(gv, 4 * l + 1);
        const int G2 = rli(gv, 4 * l + 2);
        const int G3 = rli(gv, 4 * l + 3);
        const int ga_nx = gaT[(l + 1) * 64 + lane];
        layer_body(zr, zi,
            [&](int q, int j) { return rlf(cA[j], sb + q); },
            G0, G1, G2, G3, ga, lds, lane);
        ga = ga_nx;
    }
    // ---- layer 6: gates 60..63 in cA, 64..69 in cB ----
    {
        const int G0 = rli(gv, 24), G1 = rli(gv, 25);
        const int G2 = rli(gv, 26), G3 = rli(gv, 27);
        const int ga_nx = gaT[7 * 64 + lane];
        layer_body(zr, zi,
            [&](int q, int j) {
                return (q < 4) ? rlf(cA[j], 60 + q) : rlf(cB[j], q - 4);
            },
            G0, G1, G2, G3, ga, lds, lane);
        ga = ga_nx;
    }
    // ---- layer 7: gates 70..79 in cB ----
    {
        const int G0 = rli(gv, 28), G1 = rli(gv, 29);
        const int G2 = rli(gv, 30), G3 = rli(gv, 31);
        layer_body(zr, zi,
            [&](int q, int j) { return rlf(cB[j], 6 + q); },
            G0, G1, G2, G3, ga, lds, lane);
    }

    // ---- epilogue ----
    if (interleaved) {
        float2* __restrict__ o2 = (float2*)out;
        const size_t base = ((size_t)b << 10) + (lane << 4);
#pragma unroll
        for (int k = 0; k < 8; ++k) {
            o2[base + k]     = make_float2(zr[k].x, zi[k].x);
            o2[base + k + 8] = make_float2(zr[k].y, zi[k].y);
        }
    } else {
        // harness compares real part only (complex64 expected cast to float32)
        float4* __restrict__ o4 = (float4*)(out + ((size_t)b << 10) + (lane << 4));
        o4[0] = make_float4(zr[0].x, zr[1].x, zr[2].x, zr[3].x);
        o4[1] = make_float4(zr[4].x, zr[5].x, zr[6].x, zr[7].x);
        o4[2] = make_float4(zr[0].y, zr[1].y, zr[2].y, zr[3].y);
        o4[3] = make_float4(zr[4].y, zr[5].y, zr[6].y, zr[7].y);
    }
}

extern "C" void kernel_launch(void* const* d_in, const int* in_sizes, int n_in,
                              void* d_out, int out_size, void* d_ws, size_t ws_size,
                              hipStream_t stream) {
    const float* x       = (const float*)d_in[0];   // (2048,1,32,32) f32
    const float* weights = (const float*)d_in[1];   // (8,10,3) f32
    float* out = (float*)d_out;
    const int interleaved = (out_size >= 2 * NBATCH * NSTATE) ? 1 : 0;
    (void)d_ws; (void)ws_size;

    qsim_rl<<<NBATCH, 64, 0, stream>>>(x, weights, out, interleaved);
}

// Round 7
// 105.393 us; speedup vs baseline: 1.0268x; 1.0268x over previous
//
#include <hip/hip_runtime.h>
#include <math.h>

// Quantum circuit simulator: BATCH=2048 states x 1024 complex amplitudes,
// QDEPTH=8 layers of StronglyEntanglingLayers (10 Rot gates + 10 CNOTs).
//
// Round-21 = r20 (single dispatch, readlane coeff distribution — kernel
// 57.9us) + two targeted cuts:
//  (1) Rot-gate symmetry: u11r=u00r, u11i=-u00i, u10r=-u01r, u10i=u01i
//      -> only 4 readlanes/gate (was 8); LANE_GATE coefficient selects
//      become 2 sign-XORs (c0r,c1i need no select); sign flips fold into
//      VOP3P neg modifiers in the FMA forms. ~-2.5us VALU busy.
//  (2) Wave desync: duty pinned at ~60-62% across 1/2/4 waves-per-SIMD
//      (r18/r15/r16) because co-resident waves run identical streams in
//      lockstep -> correlated stalls. s_sleep ladder on (b&7) gives any
//      two of the 8 blocks/CU distinct start offsets (~0..1.8k cyc),
//      letting one wave's gate math cover the other's DS join.
// Model: pk_fma_f32 = 4cyc/wave64 -> ~27us/SIMD busy floor at 2 waves;
// kernel = busy/duty. r20 busy 34.7us @60%; target busy ~32 @70-80%.
// Carried (validated): t-packed v2f state -> v_pk_fma with scalar coeffs;
// wires 9..7 cross-pack reg gates; wire 6 in-pack half-swap; wires 5..2
// DPP; wires 1,0 permlane{16,32}_swap; CNOT = composed GF(2)-linear perm,
// one LDS round trip, t-major word(i)=(i&15)*64+(i>>4) (conflict-free),
// merged re/im planes -> ds_*2st64 pairing; GF(2) gt-basis in one VGPR
// (4 readlane + SALU XOR per layer); ga in LDS, double-buffered; no
// barriers (single wave, per-wave DS FIFO).

#define WIRES   10
#define NSTATE  1024
#define QDEPTH  8
#define NBATCH  2048
#define NGATES  (QDEPTH * WIRES)

typedef float v2f __attribute__((ext_vector_type(2)));
typedef unsigned int v2u __attribute__((ext_vector_type(2)));
static __device__ __forceinline__ v2f s2(float x) { return (v2f){x, x}; }

__device__ __forceinline__ int perm_g(int j, int r) {
#pragma unroll
    for (int q = WIRES - 1; q >= 0; --q) {
        const int cb = 9 - q;
        const int tb = 9 - ((q + r) % WIRES);
        j ^= ((j >> cb) & 1) << tb;
    }
    return j;
}

#if __has_builtin(__builtin_amdgcn_readlane)
static __device__ __forceinline__ int rli(int v, int idx) {
    return __builtin_amdgcn_readlane(v, idx);
}
#else
static __device__ __forceinline__ int rli(int v, int idx) {
    return __shfl(v, idx, 64);
}
#endif
static __device__ __forceinline__ float rlf(float v, int idx) {
    return __int_as_float(rli(__float_as_int(v), idx));
}

// DPP cross-lane move (VALU pipe, rows of 16 lanes) — validated r9/r10/r13
template<int CTRL>
__device__ __forceinline__ float dppmov(float x) {
    return __int_as_float(__builtin_amdgcn_update_dpp(
        0, __float_as_int(x), CTRL, 0xF, 0xF, true));
}
#define FX1(v)  dppmov<0xB1>(v)
#define FX2(v)  dppmov<0x4E>(v)
#define FX4(v)  dppmov<0x1B>(dppmov<0x141>(v))
#define FX8(v)  dppmov<0x128>(v)

#if __has_builtin(__builtin_amdgcn_permlane16_swap)
static __device__ __forceinline__ float pl16swap(float x) {
    const v2u r = __builtin_amdgcn_permlane16_swap(
        __float_as_uint(x), __float_as_uint(x), false, false);
    return __uint_as_float((threadIdx.x & 16) ? r.x : r.y);
}
#define FX16(v) pl16swap(v)
#else
#define FX16(v) __shfl_xor((v), 16, 64)
#endif

#if __has_builtin(__builtin_amdgcn_permlane32_swap)
static __device__ __forceinline__ float pl32swap(float x) {
    const v2u r = __builtin_amdgcn_permlane32_swap(
        __float_as_uint(x), __float_as_uint(x), false, false);
    return __uint_as_float((threadIdx.x & 32) ? r.x : r.y);
}
#define FX32(v) pl32swap(v)
#else
#define FX32(v) __shfl_xor((v), 32, 64)
#endif

// Rot gate base coeffs: only U00,U01 stored; U10=-conj'(U01), U11=conj'(U00)
// (u10r=-u01r, u10i=u01i, u11r=u00r, u11i=-u00i).
__device__ __forceinline__ void gate_coeffs4(
    const float* __restrict__ w, int g, float (&c4)[4])
{
    const float phi   = tanhf(w[g * 3 + 0]);
    const float theta = tanhf(w[g * 3 + 1]);
    const float omega = tanhf(w[g * 3 + 2]);
    const float c  = cosf(theta * 0.5f);
    const float sn = sinf(theta * 0.5f);
    const float a  = 0.5f * (phi + omega);
    const float bb = 0.5f * (phi - omega);
    const float ca = cosf(a),  sa = sinf(a);
    const float cb = cosf(bb), sb = sinf(bb);
    c4[0] =  ca * c;   // u00r
    c4[1] = -sa * c;   // u00i
    c4[2] = -cb * sn;  // u01r
    c4[3] = -sb * sn;  // u01i
}

static __device__ __forceinline__ float sgnxor(float v, unsigned s) {
    return __uint_as_float(__float_as_uint(v) ^ s);
}

// ---- gate bodies; expect getc(q,j) (j=0..3), lane, zr, zi in scope ----
// Substituted forms (from validated originals via the symmetry):
//   zr[k1] = -u01r*a0r - u01i*a0i + u00r*a1r + u00i*a1i
//   zi[k1] = -u01r*a0i + u01i*a0r + u00r*a1i - u00i*a1r
#define LOCAL_GATE(Q, MASK)                                                   \
    {                                                                         \
        const float u00r=getc(Q,0), u00i=getc(Q,1);                           \
        const float u01r=getc(Q,2), u01i=getc(Q,3);                           \
        _Pragma("unroll")                                                     \
        for (int k0 = 0; k0 < 8; ++k0) {                                      \
            if (k0 & (MASK)) continue;                                        \
            const int k1 = k0 | (MASK);                                       \
            const v2f a0r = zr[k0], a0i = zi[k0];                             \
            const v2f a1r = zr[k1], a1i = zi[k1];                             \
            zr[k0] = s2(u00r)*a0r - s2(u00i)*a0i + s2(u01r)*a1r - s2(u01i)*a1i;\
            zi[k0] = s2(u00r)*a0i + s2(u00i)*a0r + s2(u01r)*a1i + s2(u01i)*a1r;\
            zr[k1] = s2(u00r)*a1r + s2(u00i)*a1i - s2(u01r)*a0r - s2(u01i)*a0i;\
            zi[k1] = s2(u00r)*a1i - s2(u00i)*a1r - s2(u01r)*a0i + s2(u01i)*a0r;\
        }                                                                     \
    }

// wire-6 half-swap: pAr={u00r,u11r}=s2(u00r); pAi={u00i,-u00i};
// pBr={u01r,-u01r}; pBi={u01i,u01i}=s2(u01i)
#define HSWAP_GATE(Q)                                                         \
    {                                                                         \
        const float u00r=getc(Q,0), u00i=getc(Q,1);                           \
        const float u01r=getc(Q,2), u01i=getc(Q,3);                           \
        const v2f pAr = s2(u00r);                                             \
        const v2f pAi = (v2f){u00i, -u00i};                                   \
        const v2f pBr = (v2f){u01r, -u01r};                                   \
        const v2f pBi = s2(u01i);                                             \
        _Pragma("unroll")                                                     \
        for (int k = 0; k < 8; ++k) {                                         \
            const v2f r  = zr[k], i = zi[k];                                  \
            const v2f rs = __builtin_shufflevector(r, r, 1, 0);               \
            const v2f is = __builtin_shufflevector(i, i, 1, 0);               \
            zr[k] = pAr*r - pAi*i + pBr*rs - pBi*is;                          \
            zi[k] = pAr*i + pAi*r + pBr*is + pBi*rs;                          \
        }                                                                     \
    }

// lane gate: c0r=u00r (no select), c0i=u00i^sgn, c1r=u01r^sgn, c1i=u01i
#define LANE_GATE(Q, J, FETCH)                                                \
    {                                                                         \
        const float u00r=getc(Q,0), u00i=getc(Q,1);                           \
        const float u01r=getc(Q,2), u01i=getc(Q,3);                           \
        const unsigned sgn = ((unsigned)(lane >> (J)) & 1u) << 31;            \
        const float c0r = u00r,            c0i = sgnxor(u00i, sgn);           \
        const float c1r = sgnxor(u01r, sgn), c1i = u01i;                      \
        _Pragma("unroll")                                                     \
        for (int k = 0; k < 8; ++k) {                                         \
            v2f pr, pi;                                                       \
            pr.x = FETCH(zr[k].x); pr.y = FETCH(zr[k].y);                     \
            pi.x = FETCH(zi[k].x); pi.y = FETCH(zi[k].y);                     \
            const v2f sr = zr[k], si = zi[k];                                 \
            zr[k] = s2(c0r)*sr - s2(c0i)*si + s2(c1r)*pr - s2(c1i)*pi;        \
            zi[k] = s2(c0r)*si + s2(c0i)*sr + s2(c1r)*pi + s2(c1i)*pr;        \
        }                                                                     \
    }

// one full layer: 10 rotation gates + composed-CNOT LDS round trip
template<typename GetC>
__device__ __forceinline__ void layer_body(
    v2f (&zr)[8], v2f (&zi)[8], GetC getc,
    const int G0, const int G1, const int G2, const int G3,
    const int ga, float* __restrict__ lds, const int lane)
{
    LOCAL_GATE(9, 1)
    LOCAL_GATE(8, 2)
    LOCAL_GATE(7, 4)
    HSWAP_GATE(6)
    LANE_GATE(5, 0, FX1)
    LANE_GATE(4, 1, FX2)
    LANE_GATE(3, 2, FX4)
    LANE_GATE(2, 3, FX8)
    LANE_GATE(1, 4, FX16)
    LANE_GATE(0, 5, FX32)

    // CNOT write: word(i) = t*64 + lane; 4 stores/k share base ->
    // 2x ds_write2st64_b32. Conflict-free (bank = lane mod 32).
#pragma unroll
    for (int k = 0; k < 8; ++k) {
        const int w = k * 64 + lane;
        lds[w]        = zr[k].x;
        lds[w + 512]  = zr[k].y;
        lds[w + 1024] = zi[k].x;
        lds[w + 1536] = zi[k].y;
    }
    // gt[k] = XOR of basis (SALU); single-wave DS FIFO -> no barrier.
    const int s01 = G0 ^ G1;
    const int gkt[8] = {0, G0, G1, s01, G2, G2 ^ G0, G2 ^ G1, G2 ^ s01};
#pragma unroll
    for (int k = 0; k < 8; ++k) {
        const int a0 = ga ^ gkt[k];
        const int a1 = a0 ^ G3;
        zr[k].x = lds[a0]; zi[k].x = lds[a0 + 1024];
        zr[k].y = lds[a1]; zi[k].y = lds[a1 + 1024];
    }
}

__global__ __launch_bounds__(64) void qsim_rl2(
    const float* __restrict__ x,
    const float* __restrict__ weights,
    float* __restrict__ out,
    const int interleaved)
{
    __shared__ float lds[2 * NSTATE];       // CNOT buffer: re [0,1024), im +1024
    __shared__ int   gaT[QDEPTH * 64];      // word(g_l(lane<<4)) per lane

    const int lane = threadIdx.x;           // 0..63
    const int b    = blockIdx.x;

    // ---- wave desync: distinct start offsets for the 8 blocks/CU so
    // co-resident waves' stall windows decorrelate (duty was ~60% with
    // lockstep streams). Offset = (b&7) * ~256cyc, max ~1.8k cyc.
    for (int i = 0; i < (b & 7); ++i) __builtin_amdgcn_s_sleep(4);

    // ---- prologue: 4 coeffs/gate in registers (lane g -> gate g) ----
    float cA[4], cB[4];
    gate_coeffs4(weights, lane, cA);                 // gates 0..63
    gate_coeffs4(weights, 64 + (lane & 15), cB);     // gates 64..79

    int gv;                                 // G-basis: lane = l*4+b (l<8,b<4)
    {
        const int lg = (lane >> 2) & 7;
        const int bb = lane & 3;
        const int j  = perm_g(1 << bb, lg + 1);
        gv = ((j & 15) << 6) | (j >> 4);
    }
#pragma unroll
    for (int l = 0; l < QDEPTH; ++l) {      // ranges r_l = l+1
        const int j = perm_g(lane << 4, l + 1);
        gaT[l * 64 + lane] = ((j & 15) << 6) | (j >> 4);
    }

    // ---- load 16 contiguous amplitudes (real input, imag = 0) ----
    v2f zr[8], zi[8];
    const float4* __restrict__ x4 =
        (const float4*)(x + ((size_t)b << 10) + (lane << 4));
    {
        const float4 v0 = x4[0], v1 = x4[1], v2 = x4[2], v3 = x4[3];
        zr[0].x=v0.x; zr[1].x=v0.y; zr[2].x=v0.z; zr[3].x=v0.w;
        zr[4].x=v1.x; zr[5].x=v1.y; zr[6].x=v1.z; zr[7].x=v1.w;
        zr[0].y=v2.x; zr[1].y=v2.y; zr[2].y=v2.z; zr[3].y=v2.w;
        zr[4].y=v3.x; zr[5].y=v3.y; zr[6].y=v3.z; zr[7].y=v3.w;
#pragma unroll
        for (int k = 0; k < 8; ++k) zi[k] = (v2f){0.f, 0.f};
    }

    int ga = gaT[lane];                     // layer 0 (DS FIFO after init)

    // ---- layers 0..5: all gates in cA; runtime readlane index ----
#pragma unroll 1
    for (int l = 0; l < 6; ++l) {
        const int sb = l * 10;
        const int G0 = rli(gv, 4 * l + 0);
        const int G1 = rli(gv, 4 * l + 1);
        const int G2 = rli(gv, 4 * l + 2);
        const int G3 = rli(gv, 4 * l + 3);
        const int ga_nx = gaT[(l + 1) * 64 + lane];
        layer_body(zr, zi,
            [&](int q, int j) { return rlf(cA[j], sb + q); },
            G0, G1, G2, G3, ga, lds, lane);
        ga = ga_nx;
    }
    // ---- layer 6: gates 60..63 in cA, 64..69 in cB ----
    {
        const int G0 = rli(gv, 24), G1 = rli(gv, 25);
        const int G2 = rli(gv, 26), G3 = rli(gv, 27);
        const int ga_nx = gaT[7 * 64 + lane];
        layer_body(zr, zi,
            [&](int q, int j) {
                return (q < 4) ? rlf(cA[j], 60 + q) : rlf(cB[j], q - 4);
            },
            G0, G1, G2, G3, ga, lds, lane);
        ga = ga_nx;
    }
    // ---- layer 7: gates 70..79 in cB ----
    {
        const int G0 = rli(gv, 28), G1 = rli(gv, 29);
        const int G2 = rli(gv, 30), G3 = rli(gv, 31);
        layer_body(zr, zi,
            [&](int q, int j) { return rlf(cB[j], 6 + q); },
            G0, G1, G2, G3, ga, lds, lane);
    }

    // ---- epilogue ----
    if (interleaved) {
        float2* __restrict__ o2 = (float2*)out;
        const size_t base = ((size_t)b << 10) + (lane << 4);
#pragma unroll
        for (int k = 0; k < 8; ++k) {
            o2[base + k]     = make_float2(zr[k].x, zi[k].x);
            o2[base + k + 8] = make_float2(zr[k].y, zi[k].y);
        }
    } else {
        // harness compares real part only (complex64 expected cast to float32)
        float4* __restrict__ o4 = (float4*)(out + ((size_t)b << 10) + (lane << 4));
        o4[0] = make_float4(zr[0].x, zr[1].x, zr[2].x, zr[3].x);
        o4[1] = make_float4(zr[4].x, zr[5].x, zr[6].x, zr[7].x);
        o4[2] = make_float4(zr[0].y, zr[1].y, zr[2].y, zr[3].y);
        o4[3] = make_float4(zr[4].y, zr[5].y, zr[6].y, zr[7].y);
    }
}

extern "C" void kernel_launch(void* const* d_in, const int* in_sizes, int n_in,
                              void* d_out, int out_size, void* d_ws, size_t ws_size,
                              hipStream_t stream) {
    const float* x       = (const float*)d_in[0];   // (2048,1,32,32) f32
    const float* weights = (const float*)d_in[1];   // (8,10,3) f32
    float* out = (float*)d_out;
    const int interleaved = (out_size >= 2 * NBATCH * NSTATE) ? 1 : 0;
    (void)d_ws; (void)ws_size;

    qsim_rl2<<<NBATCH, 64, 0, stream>>>(x, weights, out, interleaved);
}

// Round 8
// 104.898 us; speedup vs baseline: 1.0316x; 1.0047x over previous
//
#include <hip/hip_runtime.h>
#include <math.h>

// Quantum circuit simulator: BATCH=2048 states x 1024 complex amplitudes,
// QDEPTH=8 layers of StronglyEntanglingLayers (10 Rot gates + 10 CNOTs).
//
// Round-22 = r21 (fused dispatch, 4-readlane coeffs, Rot symmetry — kernel
// 55.0us) + per-layer DS-join pipelining:
//  (1) CNOT reads fused with NEXT layer's wire-9 gate: wire-9 pairs
//      adjacent packs, so math starts after 8 of 32 reads; the first
//      pair's 16 pk_fma cover the other 24 reads' latency. (Gates on
//      distinct wires commute -> wire-9 of layer l+1 slides into layer
//      l's read section; circuit order preserved.)
//  (2) CNOT writes fused into the wire-0 gate loop: pack k's 4 stores
//      issue as soon as pack k's math completes (overlaps packs k+1..7),
//      instead of after the full gate chain.
//  (3) s_sleep desync removed (r21: null, duty insensitive).
// Evidence base: VALU-work cuts move kernel ~1:1 (r20->r21: -2.9us for
// -4 readlanes/gate); duty pinned ~61% across 1/2/4 waves/SIMD -> the
// 39% stall is the per-layer lgkmcnt drain at the CNOT read join.
// Carried (validated): t-packed v2f state -> v_pk_fma with scalar coeffs;
// wires 9..7 cross-pack reg gates; wire 6 in-pack half-swap; wires 5..2
// DPP; wires 1,0 permlane{16,32}_swap; CNOT = composed GF(2)-linear perm,
// one LDS round trip, t-major word(i)=(i&15)*64+(i>>4) (conflict-free),
// merged re/im planes -> ds_*2st64 pairing; GF(2) gt-basis in one VGPR
// (4 readlane + SALU XOR per layer); Rot symmetry (u11=conj-ish of u00,
// u10 of u01) -> 4 readlanes/gate + sign-XOR selects; ga table in LDS;
// no barriers (single wave per block, per-wave DS FIFO ordering).

#define WIRES   10
#define NSTATE  1024
#define QDEPTH  8
#define NBATCH  2048
#define NGATES  (QDEPTH * WIRES)

typedef float v2f __attribute__((ext_vector_type(2)));
typedef unsigned int v2u __attribute__((ext_vector_type(2)));
static __device__ __forceinline__ v2f s2(float x) { return (v2f){x, x}; }

__device__ __forceinline__ int perm_g(int j, int r) {
#pragma unroll
    for (int q = WIRES - 1; q >= 0; --q) {
        const int cb = 9 - q;
        const int tb = 9 - ((q + r) % WIRES);
        j ^= ((j >> cb) & 1) << tb;
    }
    return j;
}

#if __has_builtin(__builtin_amdgcn_readlane)
static __device__ __forceinline__ int rli(int v, int idx) {
    return __builtin_amdgcn_readlane(v, idx);
}
#else
static __device__ __forceinline__ int rli(int v, int idx) {
    return __shfl(v, idx, 64);
}
#endif
static __device__ __forceinline__ float rlf(float v, int idx) {
    return __int_as_float(rli(__float_as_int(v), idx));
}

// DPP cross-lane move (VALU pipe, rows of 16 lanes) — validated r9/r10/r13
template<int CTRL>
__device__ __forceinline__ float dppmov(float x) {
    return __int_as_float(__builtin_amdgcn_update_dpp(
        0, __float_as_int(x), CTRL, 0xF, 0xF, true));
}
#define FX1(v)  dppmov<0xB1>(v)
#define FX2(v)  dppmov<0x4E>(v)
#define FX4(v)  dppmov<0x1B>(dppmov<0x141>(v))
#define FX8(v)  dppmov<0x128>(v)

#if __has_builtin(__builtin_amdgcn_permlane16_swap)
static __device__ __forceinline__ float pl16swap(float x) {
    const v2u r = __builtin_amdgcn_permlane16_swap(
        __float_as_uint(x), __float_as_uint(x), false, false);
    return __uint_as_float((threadIdx.x & 16) ? r.x : r.y);
}
#define FX16(v) pl16swap(v)
#else
#define FX16(v) __shfl_xor((v), 16, 64)
#endif

#if __has_builtin(__builtin_amdgcn_permlane32_swap)
static __device__ __forceinline__ float pl32swap(float x) {
    const v2u r = __builtin_amdgcn_permlane32_swap(
        __float_as_uint(x), __float_as_uint(x), false, false);
    return __uint_as_float((threadIdx.x & 32) ? r.x : r.y);
}
#define FX32(v) pl32swap(v)
#else
#define FX32(v) __shfl_xor((v), 32, 64)
#endif

// Rot gate base coeffs: only U00,U01 stored; u10r=-u01r, u10i=u01i,
// u11r=u00r, u11i=-u00i.
__device__ __forceinline__ void gate_coeffs4(
    const float* __restrict__ w, int g, float (&c4)[4])
{
    const float phi   = tanhf(w[g * 3 + 0]);
    const float theta = tanhf(w[g * 3 + 1]);
    const float omega = tanhf(w[g * 3 + 2]);
    const float c  = cosf(theta * 0.5f);
    const float sn = sinf(theta * 0.5f);
    const float a  = 0.5f * (phi + omega);
    const float bb = 0.5f * (phi - omega);
    const float ca = cosf(a),  sa = sinf(a);
    const float cb = cosf(bb), sb = sinf(bb);
    c4[0] =  ca * c;   // u00r
    c4[1] = -sa * c;   // u00i
    c4[2] = -cb * sn;  // u01r
    c4[3] = -sb * sn;  // u01i
}

static __device__ __forceinline__ float sgnxor(float v, unsigned s) {
    return __uint_as_float(__float_as_uint(v) ^ s);
}

// ---- gate bodies (validated r21 forms); expect getc(q,j), lane, zr, zi ----
#define LOCAL_GATE(Q, MASK)                                                   \
    {                                                                         \
        const float u00r=getc(Q,0), u00i=getc(Q,1);                           \
        const float u01r=getc(Q,2), u01i=getc(Q,3);                           \
        _Pragma("unroll")                                                     \
        for (int k0 = 0; k0 < 8; ++k0) {                                      \
            if (k0 & (MASK)) continue;                                        \
            const int k1 = k0 | (MASK);                                       \
            const v2f a0r = zr[k0], a0i = zi[k0];                             \
            const v2f a1r = zr[k1], a1i = zi[k1];                             \
            zr[k0] = s2(u00r)*a0r - s2(u00i)*a0i + s2(u01r)*a1r - s2(u01i)*a1i;\
            zi[k0] = s2(u00r)*a0i + s2(u00i)*a0r + s2(u01r)*a1i + s2(u01i)*a1r;\
            zr[k1] = s2(u00r)*a1r + s2(u00i)*a1i - s2(u01r)*a0r - s2(u01i)*a0i;\
            zi[k1] = s2(u00r)*a1i - s2(u00i)*a1r - s2(u01r)*a0i + s2(u01i)*a0r;\
        }                                                                     \
    }

#define HSWAP_GATE(Q)                                                         \
    {                                                                         \
        const float u00r=getc(Q,0), u00i=getc(Q,1);                           \
        const float u01r=getc(Q,2), u01i=getc(Q,3);                           \
        const v2f pAr = s2(u00r);                                             \
        const v2f pAi = (v2f){u00i, -u00i};                                   \
        const v2f pBr = (v2f){u01r, -u01r};                                   \
        const v2f pBi = s2(u01i);                                             \
        _Pragma("unroll")                                                     \
        for (int k = 0; k < 8; ++k) {                                         \
            const v2f r  = zr[k], i = zi[k];                                  \
            const v2f rs = __builtin_shufflevector(r, r, 1, 0);               \
            const v2f is = __builtin_shufflevector(i, i, 1, 0);               \
            zr[k] = pAr*r - pAi*i + pBr*rs - pBi*is;                          \
            zi[k] = pAr*i + pAi*r + pBr*is + pBi*rs;                          \
        }                                                                     \
    }

#define LANE_GATE(Q, J, FETCH)                                                \
    {                                                                         \
        const float u00r=getc(Q,0), u00i=getc(Q,1);                           \
        const float u01r=getc(Q,2), u01i=getc(Q,3);                           \
        const unsigned sgn = ((unsigned)(lane >> (J)) & 1u) << 31;            \
        const float c0r = u00r,              c0i = sgnxor(u00i, sgn);         \
        const float c1r = sgnxor(u01r, sgn), c1i = u01i;                      \
        _Pragma("unroll")                                                     \
        for (int k = 0; k < 8; ++k) {                                         \
            v2f pr, pi;                                                       \
            pr.x = FETCH(zr[k].x); pr.y = FETCH(zr[k].y);                     \
            pi.x = FETCH(zi[k].x); pi.y = FETCH(zi[k].y);                     \
            const v2f sr = zr[k], si = zi[k];                                 \
            zr[k] = s2(c0r)*sr - s2(c0i)*si + s2(c1r)*pr - s2(c1i)*pi;        \
            zi[k] = s2(c0r)*si + s2(c0i)*sr + s2(c1r)*pi + s2(c1i)*pr;        \
        }                                                                     \
    }

// wire-9 (t-bit0, adjacent-pack pair) on one pair, coeffs n00*/n01*
#define W9_PAIR(KA)                                                           \
    {                                                                         \
        const int kA = (KA), kB = (KA) + 1;                                   \
        const v2f a0r = zr[kA], a0i = zi[kA];                                 \
        const v2f a1r = zr[kB], a1i = zi[kB];                                 \
        zr[kA] = s2(n00r)*a0r - s2(n00i)*a0i + s2(n01r)*a1r - s2(n01i)*a1i;   \
        zi[kA] = s2(n00r)*a0i + s2(n00i)*a0r + s2(n01r)*a1i + s2(n01i)*a1r;   \
        zr[kB] = s2(n00r)*a1r + s2(n00i)*a1i - s2(n01r)*a0r - s2(n01i)*a0i;   \
        zi[kB] = s2(n00r)*a1i - s2(n00i)*a1r - s2(n01r)*a0i + s2(n01i)*a0r;   \
    }

// one layer, wires 8..0 (wire 9 handled by predecessor's read fusion),
// + CNOT write fused into wire-0 gate + reads (fused with next wire-9).
template<bool FUSE9, typename GetC, typename GetC9>
__device__ __forceinline__ void layer_mid(
    v2f (&zr)[8], v2f (&zi)[8], GetC getc, GetC9 getc9,
    const int G0, const int G1, const int G2, const int G3,
    const int ga, float* __restrict__ lds, const int lane)
{
    LOCAL_GATE(8, 2)
    LOCAL_GATE(7, 4)
    HSWAP_GATE(6)
    LANE_GATE(5, 0, FX1)
    LANE_GATE(4, 1, FX2)
    LANE_GATE(3, 2, FX4)
    LANE_GATE(2, 3, FX8)
    LANE_GATE(1, 4, FX16)

    // ---- wire-0 gate with CNOT write fused per pack: pack k's stores
    // issue right after its math (overlap with packs k+1..7) ----
    {
        const float u00r=getc(0,0), u00i=getc(0,1);
        const float u01r=getc(0,2), u01i=getc(0,3);
        const unsigned sgn = ((unsigned)(lane >> 5) & 1u) << 31;
        const float c0r = u00r,              c0i = sgnxor(u00i, sgn);
        const float c1r = sgnxor(u01r, sgn), c1i = u01i;
#pragma unroll
        for (int k = 0; k < 8; ++k) {
            v2f pr, pi;
            pr.x = FX32(zr[k].x); pr.y = FX32(zr[k].y);
            pi.x = FX32(zi[k].x); pi.y = FX32(zi[k].y);
            const v2f sr = zr[k], si = zi[k];
            zr[k] = s2(c0r)*sr - s2(c0i)*si + s2(c1r)*pr - s2(c1i)*pi;
            zi[k] = s2(c0r)*si + s2(c0i)*sr + s2(c1r)*pi + s2(c1i)*pr;
            const int w = k * 64 + lane;
            lds[w]        = zr[k].x;
            lds[w + 512]  = zr[k].y;
            lds[w + 1024] = zi[k].x;
            lds[w + 1536] = zi[k].y;
        }
    }

    // ---- CNOT reads; single-wave DS FIFO -> no barrier needed ----
    const int s01 = G0 ^ G1;
    const int gkt[8] = {0, G0, G1, s01, G2, G2 ^ G0, G2 ^ G1, G2 ^ s01};
    if constexpr (FUSE9) {
        // fused with NEXT layer's wire-9: math starts after 8 of 32 reads
        const float n00r=getc9(0), n00i=getc9(1);
        const float n01r=getc9(2), n01i=getc9(3);
#pragma unroll
        for (int k0 = 0; k0 < 8; k0 += 2) {
            const int a0 = ga ^ gkt[k0],     a1 = a0 ^ G3;
            zr[k0].x = lds[a0]; zi[k0].x = lds[a0 + 1024];
            zr[k0].y = lds[a1]; zi[k0].y = lds[a1 + 1024];
            const int b0 = ga ^ gkt[k0 + 1], b1 = b0 ^ G3;
            zr[k0+1].x = lds[b0]; zi[k0+1].x = lds[b0 + 1024];
            zr[k0+1].y = lds[b1]; zi[k0+1].y = lds[b1 + 1024];
            W9_PAIR(k0)
        }
    } else {
#pragma unroll
        for (int k = 0; k < 8; ++k) {
            const int a0 = ga ^ gkt[k];
            const int a1 = a0 ^ G3;
            zr[k].x = lds[a0]; zi[k].x = lds[a0 + 1024];
            zr[k].y = lds[a1]; zi[k].y = lds[a1 + 1024];
        }
    }
}

__global__ __launch_bounds__(64) void qsim_pl(
    const float* __restrict__ x,
    const float* __restrict__ weights,
    float* __restrict__ out,
    const int interleaved)
{
    __shared__ float lds[2 * NSTATE];       // CNOT buffer: re [0,1024), im +1024
    __shared__ int   gaT[QDEPTH * 64];      // word(g_l(lane<<4)) per lane

    const int lane = threadIdx.x;           // 0..63
    const int b    = blockIdx.x;

    // ---- prologue: 4 coeffs/gate in registers (lane g -> gate g) ----
    float cA[4], cB[4];
    gate_coeffs4(weights, lane, cA);                 // gates 0..63
    gate_coeffs4(weights, 64 + (lane & 15), cB);     // gates 64..79

    int gv;                                 // G-basis: lane = l*4+bit (l<8)
    {
        const int lg = (lane >> 2) & 7;
        const int bbit = lane & 3;
        const int j  = perm_g(1 << bbit, lg + 1);
        gv = ((j & 15) << 6) | (j >> 4);
    }
#pragma unroll
    for (int l = 0; l < QDEPTH; ++l) {      // ranges r_l = l+1
        const int j = perm_g(lane << 4, l + 1);
        gaT[l * 64 + lane] = ((j & 15) << 6) | (j >> 4);
    }

    // ---- load 16 contiguous amplitudes (real input, imag = 0) ----
    v2f zr[8], zi[8];
    const float4* __restrict__ x4 =
        (const float4*)(x + ((size_t)b << 10) + (lane << 4));
    {
        const float4 v0 = x4[0], v1 = x4[1], v2 = x4[2], v3 = x4[3];
        zr[0].x=v0.x; zr[1].x=v0.y; zr[2].x=v0.z; zr[3].x=v0.w;
        zr[4].x=v1.x; zr[5].x=v1.y; zr[6].x=v1.z; zr[7].x=v1.w;
        zr[0].y=v2.x; zr[1].y=v2.y; zr[2].y=v2.z; zr[3].y=v2.w;
        zr[4].y=v3.x; zr[5].y=v3.y; zr[6].y=v3.z; zr[7].y=v3.w;
#pragma unroll
        for (int k = 0; k < 8; ++k) zi[k] = (v2f){0.f, 0.f};
    }

    // ---- wire-9 of layer 0 (zi==0 folds to consts) ----
    {
        const float n00r = rlf(cA[0], 9), n00i = rlf(cA[1], 9);
        const float n01r = rlf(cA[2], 9), n01i = rlf(cA[3], 9);
#pragma unroll
        for (int k0 = 0; k0 < 8; k0 += 2) W9_PAIR(k0)
    }

    // ---- layers 0..4: coeffs in cA; fused next-wire-9 also in cA ----
#pragma unroll 1
    for (int l = 0; l < 5; ++l) {
        const int sb = l * 10;
        const int G0 = rli(gv, 4 * l + 0);
        const int G1 = rli(gv, 4 * l + 1);
        const int G2 = rli(gv, 4 * l + 2);
        const int G3 = rli(gv, 4 * l + 3);
        const int ga = gaT[l * 64 + lane];
        layer_mid<true>(zr, zi,
            [&](int q, int j) { return rlf(cA[j], sb + q); },
            [&](int j) { return rlf(cA[j], sb + 19); },   // gate (l+1)*10+9
            G0, G1, G2, G3, ga, lds, lane);
    }
    // ---- layer 5: cur cA@50; next wire-9 = gate 69 -> cB[5] ----
    {
        const int G0 = rli(gv, 20), G1 = rli(gv, 21);
        const int G2 = rli(gv, 22), G3 = rli(gv, 23);
        const int ga = gaT[5 * 64 + lane];
        layer_mid<true>(zr, zi,
            [&](int q, int j) { return rlf(cA[j], 50 + q); },
            [&](int j) { return rlf(cB[j], 5); },
            G0, G1, G2, G3, ga, lds, lane);
    }
    // ---- layer 6: gates 60..63 in cA, 64..69 in cB; next w9 = gate 79 ----
    {
        const int G0 = rli(gv, 24), G1 = rli(gv, 25);
        const int G2 = rli(gv, 26), G3 = rli(gv, 27);
        const int ga = gaT[6 * 64 + lane];
        layer_mid<true>(zr, zi,
            [&](int q, int j) {
                return (q < 4) ? rlf(cA[j], 60 + q) : rlf(cB[j], q - 4);
            },
            [&](int j) { return rlf(cB[j], 15); },
            G0, G1, G2, G3, ga, lds, lane);
    }
    // ---- layer 7: gates 70..79 in cB; no next layer (plain reads) ----
    {
        const int G0 = rli(gv, 28), G1 = rli(gv, 29);
        const int G2 = rli(gv, 30), G3 = rli(gv, 31);
        const int ga = gaT[7 * 64 + lane];
        layer_mid<false>(zr, zi,
            [&](int q, int j) { return rlf(cB[j], 6 + q); },
            [&](int j) { return 0.0f; },
            G0, G1, G2, G3, ga, lds, lane);
    }

    // ---- epilogue ----
    if (interleaved) {
        float2* __restrict__ o2 = (float2*)out;
        const size_t base = ((size_t)b << 10) + (lane << 4);
#pragma unroll
        for (int k = 0; k < 8; ++k) {
            o2[base + k]     = make_float2(zr[k].x, zi[k].x);
            o2[base + k + 8] = make_float2(zr[k].y, zi[k].y);
        }
    } else {
        // harness compares real part only (complex64 expected cast to float32)
        float4* __restrict__ o4 = (float4*)(out + ((size_t)b << 10) + (lane << 4));
        o4[0] = make_float4(zr[0].x, zr[1].x, zr[2].x, zr[3].x);
        o4[1] = make_float4(zr[4].x, zr[5].x, zr[6].x, zr[7].x);
        o4[2] = make_float4(zr[0].y, zr[1].y, zr[2].y, zr[3].y);
        o4[3] = make_float4(zr[4].y, zr[5].y, zr[6].y, zr[7].y);
    }
}

extern "C" void kernel_launch(void* const* d_in, const int* in_sizes, int n_in,
                              void* d_out, int out_size, void* d_ws, size_t ws_size,
                              hipStream_t stream) {
    const float* x       = (const float*)d_in[0];   // (2048,1,32,32) f32
    const float* weights = (const float*)d_in[1];   // (8,10,3) f32
    float* out = (float*)d_out;
    const int interleaved = (out_size >= 2 * NBATCH * NSTATE) ? 1 : 0;
    (void)d_ws; (void)ws_size;

    qsim_pl<<<NBATCH, 64, 0, stream>>>(x, weights, out, interleaved);
}